// Round 8
// baseline (229.704 us; speedup 1.0000x reference)
//
#include <hip/hip_runtime.h>

#define N_VOX 100000
#define K3 125
#define CENTER_K 62
#define BVOX 128
#define NBLK 782            // ceil(100000/128); last block has 32 voxels
#define EPSF 1e-5f

// ws layout (float-word offsets)
#define WIT 0               // W_img lane-order [125][4][64][4] (c = q*16+t*4+e, lane = q*16+o)
#define WPT 128000          // W_pts lane-order [125][2][64][4] (c = q*8+t*4+e)
#define WVT 192000          // W_vis lane-order [125][2][64][4]
#define LST 256000          // per-block saved lists: [NBLK][1024] ints (koff[126] @0, list @128)
#define CAT (256000 + NBLK * 1024)   // cat [NBLK*128][32] f32
// end = 1,056,768 + 3,203,072 = 4,259,840 words = 17.0 MB

#define DOT4(f_, g_) ((f_).x*(g_).x + (f_).y*(g_).y + (f_).z*(g_).z + (f_).w*(g_).w)

// transpose W into lane-order (same mapping as round 2, verified)
__global__ __launch_bounds__(256) void prep_transpose(
    const float* __restrict__ Wi, const float* __restrict__ Wp,
    const float* __restrict__ Wv, float* __restrict__ ws)
{
    int i = blockIdx.x * 256 + threadIdx.x;
    if (i < 125 * 64 * 16) {
        int k = i >> 10, r = i & 1023;
        int c = r >> 4, o = r & 15;
        int cs = c >> 4, t = (c >> 2) & 3, e = c & 3;
        ws[WIT + k * 1024 + t * 256 + (cs * 16 + o) * 4 + e] = Wi[i];
    }
    if (i < 125 * 32 * 16) {
        int k = i / 512, r = i % 512;
        int c = r >> 4, o = r & 15;
        int cs = c >> 3, t = (c >> 2) & 1, e = c & 3;
        ws[WPT + k * 512 + t * 256 + (cs * 16 + o) * 4 + e] = Wp[i];
        ws[WVT + k * 512 + t * 256 + (cs * 16 + o) * 4 + e] = Wv[i];
    }
}

// Kernel A: per-block build k-sorted pair list + img/pts conv with LDS accumulation
__global__ __launch_bounds__(512, 6) void convA(
    const float* __restrict__ fimg, const float* __restrict__ fpts,
    const int* __restrict__ nbr, float* __restrict__ ws,
    const float* __restrict__ gi, const float* __restrict__ bi,
    const float* __restrict__ mi, const float* __restrict__ vi,
    const float* __restrict__ gp, const float* __restrict__ bp,
    const float* __restrict__ mp, const float* __restrict__ vp)
{
    __shared__ int s_kcnt[128];     // counts, then placement cursors
    __shared__ int s_scan[128];
    __shared__ int s_koff[128];     // exclusive offsets; [125] = total
    __shared__ int s_list[768];     // (ln<<17)|j
    __shared__ float s_acc[BVOX][32];
    __shared__ int s_next;

    const int tid = threadIdx.x, lane = tid & 63, wv = tid >> 6;
    const int blk = blockIdx.x;
    const int gbase = blk * BVOX;
    const int vcount = min(BVOX, N_VOX - gbase);
    const int q = lane >> 4;

    if (tid < 128) s_kcnt[tid] = 0;
    if (tid == 0) s_next = 0;
    __syncthreads();

    // pass 1: count valid non-center taps per k
    const int TOTE = vcount * K3;
    const int* nrow = nbr + (size_t)gbase * K3;
    for (int e = tid; e < TOTE; e += 512) {
        int idx = nrow[e];
        int k = e % K3;
        if (idx < N_VOX && k != CENTER_K) atomicAdd(&s_kcnt[k], 1);
    }
    __syncthreads();

    // inclusive Hillis-Steele scan over 125 counts
    if (tid < 128) s_scan[tid] = (tid < K3) ? s_kcnt[tid] : 0;
    __syncthreads();
    for (int d = 1; d < 128; d <<= 1) {
        int v = 0;
        if (tid < 128 && tid >= d) v = s_scan[tid - d];
        __syncthreads();
        if (tid < 128) s_scan[tid] += v;
        __syncthreads();
    }
    if (tid < 128) s_koff[tid] = (tid == 0) ? 0 : s_scan[tid - 1];
    __syncthreads();
    if (tid < 128) s_kcnt[tid] = s_koff[tid];   // cursors
    __syncthreads();

    // pass 2: place (L2-warm re-read of this block's 64KB nbr chunk)
    for (int e = tid; e < TOTE; e += 512) {
        int idx = nrow[e];
        int k = e % K3;
        if (idx < N_VOX && k != CENTER_K) {
            int ln = e / K3;
            int pos = atomicAdd(&s_kcnt[k], 1);
            s_list[pos] = (ln << 17) | idx;
        }
    }
    __syncthreads();

    // save koff + list for kernel B
    {
        int tot = s_koff[K3];
        int* dst = (int*)(ws + LST) + (size_t)blk * 1024;
        if (tid < 126) dst[tid] = s_koff[tid];
        for (int p = tid; p < tot; p += 512) dst[128 + p] = s_list[p];
    }

    const float4* __restrict__ fi4 = (const float4*)fimg;
    const float4* __restrict__ fp4 = (const float4*)fpts;

    // center phase: wave wv owns voxels ln = wv*16..+15; INIT s_acc (replaces zeroing)
    {
        float4 cwi[4], cwp[2];
        const float4* WI4 = (const float4*)(ws + WIT + CENTER_K * 1024);
        const float4* WP4 = (const float4*)(ws + WPT + CENTER_K * 512);
        #pragma unroll
        for (int t = 0; t < 4; ++t) cwi[t] = WI4[t * 64 + lane];
        #pragma unroll
        for (int t = 0; t < 2; ++t) cwp[t] = WP4[t * 64 + lane];
        for (int i = 0; i < 16; ++i) {
            int ln = wv * 16 + i;
            if (ln >= vcount) break;
            int n = gbase + ln;
            const float4* fr = fi4 + (size_t)n * 16 + q * 4;
            const float4* gr = fp4 + (size_t)n * 8 + q * 2;
            float aI = DOT4(fr[0], cwi[0]) + DOT4(fr[1], cwi[1])
                     + DOT4(fr[2], cwi[2]) + DOT4(fr[3], cwi[3]);
            float aP = DOT4(gr[0], cwp[0]) + DOT4(gr[1], cwp[1]);
            aI += __shfl_xor(aI, 16); aI += __shfl_xor(aI, 32);
            aP += __shfl_xor(aP, 16); aP += __shfl_xor(aP, 32);
            if (lane < 32) s_acc[ln][lane] = (lane < 16) ? aI : aP;
        }
    }
    __syncthreads();

    // segment phase: waves dynamically grab k-segments; W[k] in regs
    while (true) {
        int s;
        if (lane == 0) s = atomicAdd(&s_next, 1);
        s = __shfl(s, 0);
        if (s >= K3) break;
        int pbeg = s_koff[s], pend = s_koff[s + 1];
        if (pbeg == pend) continue;
        float4 swi[4], swp[2];
        const float4* WI4 = (const float4*)(ws + WIT + s * 1024);
        const float4* WP4 = (const float4*)(ws + WPT + s * 512);
        #pragma unroll
        for (int t = 0; t < 4; ++t) swi[t] = WI4[t * 64 + lane];
        #pragma unroll
        for (int t = 0; t < 2; ++t) swp[t] = WP4[t * 64 + lane];
        for (int p = pbeg; p < pend; ++p) {
            int ent = s_list[p];
            int ln = ent >> 17, j = ent & 0x1FFFF;
            const float4* fr = fi4 + (size_t)j * 16 + q * 4;
            const float4* gr = fp4 + (size_t)j * 8 + q * 2;
            float aI = DOT4(fr[0], swi[0]) + DOT4(fr[1], swi[1])
                     + DOT4(fr[2], swi[2]) + DOT4(fr[3], swi[3]);
            float aP = DOT4(gr[0], swp[0]) + DOT4(gr[1], swp[1]);
            aI += __shfl_xor(aI, 16); aI += __shfl_xor(aI, 32);
            aP += __shfl_xor(aP, 16); aP += __shfl_xor(aP, 32);
            if (lane < 32) atomicAdd(&s_acc[ln][lane], (lane < 16) ? aI : aP);
        }
    }
    __syncthreads();

    // finalize: BN + ReLU -> cat
    {
        int c = tid & 31;
        float g, b, m, v;
        if (c < 16) { g = gi[c]; b = bi[c]; m = mi[c]; v = vi[c]; }
        else        { g = gp[c - 16]; b = bp[c - 16]; m = mp[c - 16]; v = vp[c - 16]; }
        float sc = g * rsqrtf(v + EPSF);
        float* cat = ws + CAT;
        for (int r = 0; r < 8; ++r) {
            int ln = (tid >> 5) + r * 16;
            if (ln < vcount)
                cat[(size_t)(gbase + ln) * 32 + c] =
                    fmaxf((s_acc[ln][c] - m) * sc + b, 0.f);
        }
    }
}

// Kernel B: vis conv on cat (reusing saved lists) + BN/ReLU + sigmoid + blend
__global__ __launch_bounds__(512, 6) void convB(
    float* __restrict__ ws,
    const float* __restrict__ gv, const float* __restrict__ bv,
    const float* __restrict__ mv, const float* __restrict__ vv,
    const float* __restrict__ w2, float* __restrict__ out)
{
    __shared__ int s_koff[128];
    __shared__ int s_list[768];
    __shared__ float s_acc[BVOX][16];
    __shared__ int s_next;

    const int tid = threadIdx.x, lane = tid & 63, wv = tid >> 6;
    const int blk = blockIdx.x;
    const int gbase = blk * BVOX;
    const int vcount = min(BVOX, N_VOX - gbase);
    const int q = lane >> 4, o = lane & 15;

    const int* src = (const int*)(ws + LST) + (size_t)blk * 1024;
    if (tid < 126) s_koff[tid] = src[tid];
    if (tid == 0) s_next = 0;
    __syncthreads();
    int tot = s_koff[K3];
    for (int p = tid; p < tot; p += 512) s_list[p] = src[128 + p];

    const float4* __restrict__ c4 = (const float4*)(ws + CAT);

    // center phase: INIT s_acc
    {
        float4 cwv[2];
        const float4* WV4 = (const float4*)(ws + WVT + CENTER_K * 512);
        #pragma unroll
        for (int t = 0; t < 2; ++t) cwv[t] = WV4[t * 64 + lane];
        for (int i = 0; i < 16; ++i) {
            int ln = wv * 16 + i;
            if (ln >= vcount) break;
            int n = gbase + ln;
            const float4* cr = c4 + (size_t)n * 8 + q * 2;
            float aV = DOT4(cr[0], cwv[0]) + DOT4(cr[1], cwv[1]);
            aV += __shfl_xor(aV, 16); aV += __shfl_xor(aV, 32);
            if (lane < 16) s_acc[ln][o] = aV;
        }
    }
    __syncthreads();   // also covers s_list load completion

    // segment phase
    while (true) {
        int s;
        if (lane == 0) s = atomicAdd(&s_next, 1);
        s = __shfl(s, 0);
        if (s >= K3) break;
        int pbeg = s_koff[s], pend = s_koff[s + 1];
        if (pbeg == pend) continue;
        float4 swv[2];
        const float4* WV4 = (const float4*)(ws + WVT + s * 512);
        #pragma unroll
        for (int t = 0; t < 2; ++t) swv[t] = WV4[t * 64 + lane];
        for (int p = pbeg; p < pend; ++p) {
            int ent = s_list[p];
            int ln = ent >> 17, j = ent & 0x1FFFF;
            const float4* cr = c4 + (size_t)j * 8 + q * 2;
            float aV = DOT4(cr[0], swv[0]) + DOT4(cr[1], swv[1]);
            aV += __shfl_xor(aV, 16); aV += __shfl_xor(aV, 32);
            if (lane < 16) atomicAdd(&s_acc[ln][o], aV);
        }
    }
    __syncthreads();

    // finalize: BN + ReLU + sigmoid gate + blend -> out
    {
        float sV = gv[o] * rsqrtf(vv[o] + EPSF);
        float bV = bv[o], mV = mv[o], w2_ = w2[o];
        const float* cat = ws + CAT;
        for (int r = 0; r < 4; ++r) {
            int ln = (tid >> 4) + r * 32;
            float h = 0.f, xi = 0.f, xp = 0.f;
            if (ln < vcount) {
                int n = gbase + ln;
                h = fmaxf((s_acc[ln][o] - mV) * sV + bV, 0.f);
                xi = cat[(size_t)n * 32 + o];
                xp = cat[(size_t)n * 32 + 16 + o];
            }
            float ph = h * w2_;
            ph += __shfl_xor(ph, 1); ph += __shfl_xor(ph, 2);
            ph += __shfl_xor(ph, 4); ph += __shfl_xor(ph, 8);
            if (ln < vcount) {
                float vis = 1.f / (1.f + expf(-ph));
                out[(size_t)(gbase + ln) * 16 + o] = vis * xi + (1.f - vis) * xp;
            }
        }
    }
}

extern "C" void kernel_launch(void* const* d_in, const int* in_sizes, int n_in,
                              void* d_out, int out_size, void* d_ws, size_t ws_size,
                              hipStream_t stream) {
    const float* fimg = (const float*)d_in[0];
    const float* fpts = (const float*)d_in[1];
    const int*   nbr  = (const int*)d_in[2];
    const float* Wimg = (const float*)d_in[3];
    const float* gi = (const float*)d_in[4];
    const float* bi = (const float*)d_in[5];
    const float* mi = (const float*)d_in[6];
    const float* vi = (const float*)d_in[7];
    const float* Wpts = (const float*)d_in[8];
    const float* gp = (const float*)d_in[9];
    const float* bp = (const float*)d_in[10];
    const float* mp = (const float*)d_in[11];
    const float* vp = (const float*)d_in[12];
    const float* Wvis = (const float*)d_in[13];
    const float* gv = (const float*)d_in[14];
    const float* bv = (const float*)d_in[15];
    const float* mv = (const float*)d_in[16];
    const float* vv = (const float*)d_in[17];
    const float* w2 = (const float*)d_in[18];
    float* out = (float*)d_out;
    float* ws = (float*)d_ws;

    hipLaunchKernelGGL(prep_transpose, dim3(500), dim3(256), 0, stream,
                       Wimg, Wpts, Wvis, ws);
    hipLaunchKernelGGL(convA, dim3(NBLK), dim3(512), 0, stream,
                       fimg, fpts, nbr, ws, gi, bi, mi, vi, gp, bp, mp, vp);
    hipLaunchKernelGGL(convB, dim3(NBLK), dim3(512), 0, stream,
                       ws, gv, bv, mv, vv, w2, out);
}